// Round 1
// baseline (201.432 us; speedup 1.0000x reference)
//
#include <hip/hip_runtime.h>

// 2-layer EfficientKAN fused via tabulation — SINGLE-KERNEL version.
//
// The whole net is a fixed scalar->scalar map f(x) (weights constant per
// launch):
//   phase 1 (blocks 0..31): evaluate exact f at 4 Lagrange nodes per interval
//            over [XLO,XHI], fit per-interval monomial cubics -> LUT in d_ws
//            (2048 intervals x float4 = 32 KB).
//   handshake: builder blocks post {MAGIC1,MAGIC2} flag pairs (device-scope
//            release); all blocks spin-acquire. Two DIFFERENT magics at two
//            addresses => a uniform poison fill can never spuriously satisfy
//            the condition. Stale flags from a previous iteration are benign:
//            the LUT is a pure function of the fixed weights, so a stale LUT
//            read is byte-identical.
//   phase 2 (all 256 blocks): stage LUT in LDS; per sample: index +
//            ds_read_b128 + Horner. Grid-stride over float4s.
//
// Deadlock safety: 256 blocks, <=1 block/CU required for co-residency;
// LDS 32 KB -> >=5 blocks/CU capacity; worst-case VGPR -> >=1 block/CU.
// All blocks resident => builders always make progress.
//
// Fit error ~h^3*|f'''| ~ 1e-5 << threshold. x ~ N(0,1), max|x| ~ 4.7 over
// 524288 samples -> [-9,9] covers with margin; out-of-range clamps.

#define NKNOT 12
#define NB 8           // GRID_SIZE + SPLINE_ORDER
#define NINT 2048
#define XLO  (-9.0f)
#define XHI  (9.0f)
#define HSTEP ((XHI - XLO) / (float)NINT)   // 18/2048
#define INVH ((float)NINT / (XHI - XLO))

#define NBLK 256
#define BUILD_BLOCKS 32           // 32*256 = 8192 = NINT*4 node evals
#define MAGIC1 0x1357ACE5u
#define MAGIC2 0x2468BD1Fu

// ---- exact reference computation (unchanged from verified kernel) ----

__device__ __forceinline__ void bspline8(float t, float b[NB]) {
    float g[NKNOT];
#pragma unroll
    for (int j = 0; j < NKNOT; ++j) g[j] = (float)(j - 3) * 0.4f - 1.0f;

    float cur[NKNOT - 1];
#pragma unroll
    for (int j = 0; j < NKNOT - 1; ++j)
        cur[j] = (t >= g[j] && t < g[j + 1]) ? 1.0f : 0.0f;

#pragma unroll
    for (int k = 1; k <= 3; ++k) {
#pragma unroll
        for (int j = 0; j < NKNOT - 1 - k; ++j) {
            const float invl = 1.0f / (g[j + k] - g[j]);         // const-folded
            const float invr = 1.0f / (g[j + k + 1] - g[j + 1]); // const-folded
            cur[j] = (t - g[j]) * invl * cur[j] +
                     (g[j + k + 1] - t) * invr * cur[j + 1];
        }
    }
#pragma unroll
    for (int j = 0; j < NB; ++j) b[j] = cur[j];
}

__device__ __forceinline__ float silu_f(float x) {
    return x / (1.0f + __expf(-x));
}

__device__ __forceinline__ float kan2_eval(float xv,
                           const float* __restrict__ bw1,
                           const float* __restrict__ sw1,
                           const float* __restrict__ sc1,
                           const float* __restrict__ bw2,
                           const float* __restrict__ sw2,
                           const float* __restrict__ sc2) {
    float bs[NB];
    bspline8(xv, bs);
    float sx = silu_f(xv);

    float h[8];
#pragma unroll
    for (int o = 0; o < 8; ++o) {
        float acc = sx * bw1[o];
        float sc = sc1[o];
#pragma unroll
        for (int k = 0; k < NB; ++k)
            acc += bs[k] * (sw1[o * NB + k] * sc);
        h[o] = acc;
    }

    float acc = 0.0f;
#pragma unroll
    for (int o = 0; o < 8; ++o) {
        float hv = h[o];
        acc += silu_f(hv) * bw2[o];
        float bs2[NB];
        bspline8(hv, bs2);
        float sc = sc2[o];
#pragma unroll
        for (int k = 0; k < NB; ++k)
            acc += bs2[k] * (sw2[o * NB + k] * sc);
    }
    return acc;
}

__device__ __forceinline__ float4 horner4(const float4* slut, float4 xv) {
    float v[4] = {xv.x, xv.y, xv.z, xv.w};
    float o[4];
#pragma unroll
    for (int c = 0; c < 4; ++c) {
        float s = (v[c] - XLO) * INVH;
        s = fminf(fmaxf(s, 0.0f), (float)NINT - 0.5f);
        int j = (int)s;
        float u = s - (float)j;
        float4 cf = slut[j];
        o[c] = ((cf.w * u + cf.z) * u + cf.y) * u + cf.x;
    }
    float4 r; r.x = o[0]; r.y = o[1]; r.z = o[2]; r.w = o[3];
    return r;
}

// ---- fused kernel: build LUT (blocks 0..31) -> flag handshake -> apply ----

__global__ __launch_bounds__(256) void kan2_fused(
    const float* __restrict__ bw1, const float* __restrict__ sw1,
    const float* __restrict__ sc1, const float* __restrict__ bw2,
    const float* __restrict__ sw2, const float* __restrict__ sc2,
    float4* __restrict__ lut, unsigned int* __restrict__ flags,
    const float4* __restrict__ x4, float4* __restrict__ out4, int n4)
{
    __shared__ float4 slut[NINT];
    const int t   = threadIdx.x;
    const int bid = blockIdx.x;
    const int gid = bid * 256 + t;

    // ---- phase 1: builder blocks evaluate exact f at cubic-fit nodes ----
    if (bid < BUILD_BLOCKS) {
        int j = gid >> 2;      // interval 0..2047
        int n = gid & 3;       // node 0..3 (u = 0, 1/3, 2/3, 1)
        float tt = XLO + ((float)j + (float)n * (1.0f / 3.0f)) * HSTEP;

        float y = kan2_eval(tt, bw1, sw1, sc1, bw2, sw2, sc2);

        int lane = t & 63;
        int base = lane & ~3;          // quads never straddle a wave (64|256)
        float y0 = __shfl(y, base + 0);
        float y1 = __shfl(y, base + 1);
        float y2 = __shfl(y, base + 2);
        float y3 = __shfl(y, base + 3);

        if (n == 0) {
            // Lagrange nodes {0,1/3,2/3,1} -> monomial coefficients
            float4 c;
            c.x = y0;
            c.y = 0.5f * (-11.0f * y0 + 18.0f * y1 - 9.0f * y2 + 2.0f * y3);
            c.z = 0.5f * ( 18.0f * y0 - 45.0f * y1 + 36.0f * y2 - 9.0f * y3);
            c.w = 0.5f * ( -9.0f * y0 + 27.0f * y1 - 27.0f * y2 + 9.0f * y3);
            lut[j] = c;
        }
        __syncthreads();               // all quad-leader stores issued
        if (t == 0) {
            // device-scope release: LUT stores happen-before flag visibility
            __hip_atomic_store(&flags[2 * bid + 1], MAGIC2,
                               __ATOMIC_RELEASE, __HIP_MEMORY_SCOPE_AGENT);
            __hip_atomic_store(&flags[2 * bid + 0], MAGIC1,
                               __ATOMIC_RELEASE, __HIP_MEMORY_SCOPE_AGENT);
        }
    }

    // ---- preload this thread's x while the LUT finishes (x is ready) ----
    const int stride = NBLK * 256;     // 65536 float4 / sweep
    int i0 = gid;
    int i1 = gid + stride;
    bool va = i0 < n4, vb = i1 < n4;
    float4 xa, xb;
    if (va) xa = x4[i0];
    if (vb) xb = x4[i1];

    // ---- handshake: wait until all 32 builder blocks posted both magics ----
    if (t == 0) {
        for (int b = 0; b < BUILD_BLOCKS; ++b) {
            while (__hip_atomic_load(&flags[2 * b + 0], __ATOMIC_ACQUIRE,
                                     __HIP_MEMORY_SCOPE_AGENT) != MAGIC1)
                __builtin_amdgcn_s_sleep(1);
            while (__hip_atomic_load(&flags[2 * b + 1], __ATOMIC_ACQUIRE,
                                     __HIP_MEMORY_SCOPE_AGENT) != MAGIC2)
                __builtin_amdgcn_s_sleep(1);
        }
    }
    __syncthreads();                   // block happens-after thread 0's acquire

    // ---- stage LUT in LDS ----
#pragma unroll
    for (int k = 0; k < NINT / 256; ++k)
        slut[t + k * 256] = lut[t + k * 256];
    __syncthreads();

    // ---- apply ----
    if (va) out4[i0] = horner4(slut, xa);
    if (vb) out4[i1] = horner4(slut, xb);
    for (int i = gid + 2 * stride; i < n4; i += stride)   // robustness tail
        out4[i] = horner4(slut, x4[i]);
}

extern "C" void kernel_launch(void* const* d_in, const int* in_sizes, int n_in,
                              void* d_out, int out_size, void* d_ws, size_t ws_size,
                              hipStream_t stream) {
    const float* x   = (const float*)d_in[0];
    const float* bw1 = (const float*)d_in[1];
    const float* sw1 = (const float*)d_in[2];
    const float* sc1 = (const float*)d_in[3];
    const float* bw2 = (const float*)d_in[4];
    const float* sw2 = (const float*)d_in[5];
    const float* sc2 = (const float*)d_in[6];
    float* out = (float*)d_out;

    float4* lut = (float4*)d_ws;                                   // 32 KB
    unsigned int* flags =
        (unsigned int*)((char*)d_ws + NINT * sizeof(float4));      // 64 ints

    int n = in_sizes[0];           // B = 524288, divisible by 4
    int n4 = n / 4;

    kan2_fused<<<NBLK, 256, 0, stream>>>(
        bw1, sw1, sc1, bw2, sw2, sc2, lut, flags,
        (const float4*)x, (float4*)out, n4);
}

// Round 2
// 70.880 us; speedup vs baseline: 2.8419x; 2.8419x over previous
//
#include <hip/hip_runtime.h>

// 2-layer EfficientKAN — DIRECT exact evaluation, single kernel, no LUT.
//
// Post-mortem R1: cross-block flag handshake cost ~150 us (agent-scope
// acquire spin = per-iteration cache-invalidate storm across 256 blocks).
// R1 also measured the graph's fixed overhead: 201.4 total - 40.3 fill
// - 157.0 kernel = ~4.2 us. So R0's two-kernel path spent ~29 us in
// build+apply+gap. This version removes the LUT machinery entirely.
//
// Key observation: the spline grid is UNIFORM (knots t_j = 0.4*(j-3)-1.0,
// j=0..11, i.e. -2.2..2.2 step 0.4, no repeated end knots). For any input
// only 4 of the 8 cubic B-splines are nonzero, and on a uniform knot
// vector they are the closed-form uniform cubic B-spline polynomials:
//   k=c-3: (1-u)^3/6   k=c-2: (3u^3-6u^2+4)/6
//   k=c-1: (-3u^3+3u^2+3u+1)/6   k=c: u^3/6
// where c = floor((x+2.2)/0.4), u = frac. Outside [-2.2,2.2) all basis
// values are zero (reference's indicator init gives all-false) — handled
// here by guard-padded ZERO rows in the LDS weight tables + index clamp,
// so no per-term masks are needed.
//
// Cost per sample ~400 VALU + 40 LDS reads (vs ~2200 VALU for the naive
// Cox-de Boor recursion) -> issue-bound ~3 us for 524288 samples.
// Numerics: exact fp32 math (v_rcp 1-ulp, __expf ~2-ulp), absmax ~1e-5.

__device__ __forceinline__ float silu_fast(float x) {
    // x * sigmoid(x); rcp is the 1-ulp v_rcp_f32 — fine vs 7.3e-3 threshold.
    return x * __builtin_amdgcn_rcpf(1.0f + __expf(-x));
}

__global__ __launch_bounds__(256) void kan2_direct(
    const float* __restrict__ bw1, const float* __restrict__ sw1,
    const float* __restrict__ sc1, const float* __restrict__ bw2,
    const float* __restrict__ sw2, const float* __restrict__ sc2,
    const float4* __restrict__ x4, float4* __restrict__ out4, int n4)
{
    // Guard-padded scaled weights. Row r = k+3, r=0..13; rows 0..2 and
    // 11..13 are ZERO guards so out-of-support k reads contribute 0.
    __shared__ __align__(16) float w1s[14 * 8];   // [r][o] : layer-1 sw*sc
    __shared__ __align__(16) float w2s[14 * 8];   // [r][i] : layer-2 sw*sc
    const int t = threadIdx.x;
    if (t < 14 * 8) {
        int r = t >> 3, c = t & 7;
        float v1 = 0.0f, v2 = 0.0f;
        if (r >= 3 && r <= 10) {
            int k = r - 3;
            v1 = sw1[c * 8 + k] * sc1[c];
            v2 = sw2[c * 8 + k] * sc2[c];
        }
        w1s[t] = v1;
        w2s[t] = v2;
    }
    __syncthreads();

    // Uniform scalars -> registers (uniform address, scalarizes to s_load).
    float bw1v[8], bw2v[8];
#pragma unroll
    for (int o = 0; o < 8; ++o) { bw1v[o] = bw1[o]; bw2v[o] = bw2[o]; }

    for (int i = blockIdx.x * 256 + t; i < n4; i += gridDim.x * 256) {
        float4 xv = x4[i];
        float vin[4] = {xv.x, xv.y, xv.z, xv.w};
        float vout[4];
#pragma unroll
        for (int cpt = 0; cpt < 4; ++cpt) {
            float x = vin[cpt];

            // ---- layer 1: h_o = silu(x)*bw1_o + sum_k B_k(x)*w1s[k][o] ----
            float s = __fmaf_rn(x, 2.5f, 5.5f);          // (x+2.2)/0.4
            s = fminf(fmaxf(s, -20.0f), 40.0f);          // int-cvt safety
            float fc = floorf(s);
            float u  = s - fc;
            int cell = (int)fc;                          // r0 = cell (=k0+3)
            float u2 = u * u, u3 = u2 * u;
            float omu = 1.0f - u;
            float n0 = omu * omu * omu * (1.0f / 6.0f);
            float n3 = u3 * (1.0f / 6.0f);
            float n1 = __fmaf_rn(__fmaf_rn(u, 0.5f, -1.0f), u2, 2.0f / 3.0f);
            float n2 = 1.0f - n0 - n1 - n3;              // partition of unity
            float nb[4] = {n0, n1, n2, n3};

            float sx = silu_fast(x);
            float h[8];
#pragma unroll
            for (int o = 0; o < 8; ++o) h[o] = sx * bw1v[o];
#pragma unroll
            for (int m = 0; m < 4; ++m) {
                int r = min(max(cell + m, 0), 13);       // guard rows are 0
                const float4 wa = *(const float4*)&w1s[r * 8];
                const float4 wb = *(const float4*)&w1s[r * 8 + 4];
                float bm = nb[m];
                h[0] = __fmaf_rn(bm, wa.x, h[0]);
                h[1] = __fmaf_rn(bm, wa.y, h[1]);
                h[2] = __fmaf_rn(bm, wa.z, h[2]);
                h[3] = __fmaf_rn(bm, wa.w, h[3]);
                h[4] = __fmaf_rn(bm, wb.x, h[4]);
                h[5] = __fmaf_rn(bm, wb.y, h[5]);
                h[6] = __fmaf_rn(bm, wb.z, h[6]);
                h[7] = __fmaf_rn(bm, wb.w, h[7]);
            }

            // ---- layer 2: out = sum_i silu(h_i)*bw2_i + spline(h_i) ----
            float acc = 0.0f;
#pragma unroll
            for (int o = 0; o < 8; ++o) {
                float hv = h[o];
                acc = __fmaf_rn(silu_fast(hv), bw2v[o], acc);
                float s2 = __fmaf_rn(hv, 2.5f, 5.5f);
                s2 = fminf(fmaxf(s2, -20.0f), 40.0f);
                float fc2 = floorf(s2);
                float uu  = s2 - fc2;
                int c2 = (int)fc2;
                float uu2 = uu * uu, uu3 = uu2 * uu;
                float womu = 1.0f - uu;
                float q0 = womu * womu * womu * (1.0f / 6.0f);
                float q3 = uu3 * (1.0f / 6.0f);
                float q1 = __fmaf_rn(__fmaf_rn(uu, 0.5f, -1.0f), uu2,
                                     2.0f / 3.0f);
                float q2 = 1.0f - q0 - q1 - q3;
                float qb[4] = {q0, q1, q2, q3};
#pragma unroll
                for (int m = 0; m < 4; ++m) {
                    int r = min(max(c2 + m, 0), 13);
                    acc = __fmaf_rn(qb[m], w2s[r * 8 + o], acc);
                }
            }
            vout[cpt] = acc;
        }
        float4 r4;
        r4.x = vout[0]; r4.y = vout[1]; r4.z = vout[2]; r4.w = vout[3];
        out4[i] = r4;
    }
}

extern "C" void kernel_launch(void* const* d_in, const int* in_sizes, int n_in,
                              void* d_out, int out_size, void* d_ws, size_t ws_size,
                              hipStream_t stream) {
    const float* x   = (const float*)d_in[0];
    const float* bw1 = (const float*)d_in[1];
    const float* sw1 = (const float*)d_in[2];
    const float* sc1 = (const float*)d_in[3];
    const float* bw2 = (const float*)d_in[4];
    const float* sw2 = (const float*)d_in[5];
    const float* sc2 = (const float*)d_in[6];
    float* out = (float*)d_out;
    (void)d_ws; (void)ws_size;

    int n  = in_sizes[0];          // B = 524288, divisible by 4
    int n4 = n / 4;                // 131072 -> 512 blocks x 256 thr, 1 float4/thr

    kan2_direct<<<(n4 + 255) / 256, 256, 0, stream>>>(
        bw1, sw1, sc1, bw2, sw2, sc2,
        (const float4*)x, (float4*)out, n4);
}

// Round 4
// 69.807 us; speedup vs baseline: 2.8855x; 1.0154x over previous
//
#include <hip/hip_runtime.h>

// 2-layer EfficientKAN — exact per-cell monomial evaluation, single kernel.
//
// R2 post-mortem: kernel ~26 us (70.9 total - 44.4 fixed from R1 calib).
// Cause: per-lane data-dependent LDS indexing w[r][o] with lanes sharing o,
// differing in r -> bank = (8r+o)%32 hits only 4 bank groups -> ~16-way
// conflicts on ~160 LDS ops/thread, at 2 waves/SIMD occupancy.
//
// R3 was an infra failure (container acquisition), not a kernel fault —
// this is the same kernel resubmitted.
//
// This version:
//  * The spline grid is uniform (knots -2.2..2.2 step 0.4), so each
//    scalar->scalar spline map is EXACTLY a cubic polynomial per cell
//    (14 cells incl. guards). Per (cell,out) we precompute monomial coeffs
//    float4 from the uniform B-spline pieces:
//      M0=(1,-3,3,-1)/6  M1=(4,0,-6,3)/6  M2=(1,3,3,-3)/6  M3=(0,0,0,1)/6
//    Eval = 1 ds_read_b128 + Horner(3 FMA). 16 LDS ops/thread total.
//  * Row stride 9 float4s (9 = 1 mod 8) -> bank group (cell+o)%8: spread
//    across all 8 groups -> conflict-free-ish b128 reads.
//  * 1 float/thread, 2048 blocks -> 8 blocks/CU, 8 waves/SIMD latency hiding.
//  * Tables built in-block by first 112 threads (~50 cycles, L2-cached
//    weight reads), no extra kernel, no d_ws, no handshake.
//
// Out-of-range: s=(x+2.2)/0.4 clamped to [0, 13.9999]; cells 11..13 and the
// u=0 end of cell 0 are exactly zero (guard k's contribute nothing), matching
// the reference's zero-outside-support behavior.

__device__ __forceinline__ float silu_fast(float x) {
    return x * __builtin_amdgcn_rcpf(1.0f + __expf(-x));
}

#define STRIDE 9   // float4s per cell row; 9 % 8 == 1 -> bank spread

__global__ __launch_bounds__(256) void kan2_cell(
    const float* __restrict__ bw1, const float* __restrict__ sw1,
    const float* __restrict__ sc1, const float* __restrict__ bw2,
    const float* __restrict__ sw2, const float* __restrict__ sc2,
    const float* __restrict__ x, float* __restrict__ out, int n)
{
    __shared__ __align__(16) float4 c1[14 * STRIDE];  // layer-1 spline coeffs
    __shared__ __align__(16) float4 c2[14 * STRIDE];  // layer-2 spline coeffs
    const int t = threadIdx.x;

    // ---- build exact per-cell monomial tables (first 112 threads) ----
    if (t < 112) {
        int c = t >> 3, o = t & 7;       // cell 0..13, output/input 0..7
        float w1v[4], w2v[4];
#pragma unroll
        for (int m = 0; m < 4; ++m) {
            int k = c - 3 + m;           // basis index contributing piece m
            bool in = (k >= 0) && (k <= 7);
            w1v[m] = in ? sw1[o * 8 + k] * sc1[o] : 0.0f;
            w2v[m] = in ? sw2[o * 8 + k] * sc2[o] : 0.0f;
        }
        float4 a1, a2;
        a1.x = (w1v[0] + 4.0f * w1v[1] + w1v[2]) * (1.0f / 6.0f);
        a1.y = (w1v[2] - w1v[0]) * 0.5f;
        a1.z = (w1v[0] + w1v[2]) * 0.5f - w1v[1];
        a1.w = (w1v[3] - w1v[0] + 3.0f * (w1v[1] - w1v[2])) * (1.0f / 6.0f);
        a2.x = (w2v[0] + 4.0f * w2v[1] + w2v[2]) * (1.0f / 6.0f);
        a2.y = (w2v[2] - w2v[0]) * 0.5f;
        a2.z = (w2v[0] + w2v[2]) * 0.5f - w2v[1];
        a2.w = (w2v[3] - w2v[0] + 3.0f * (w2v[1] - w2v[2])) * (1.0f / 6.0f);
        c1[c * STRIDE + o] = a1;
        c2[c * STRIDE + o] = a2;
    }
    __syncthreads();

    // uniform base weights -> scalar regs
    float bw1v[8], bw2v[8];
#pragma unroll
    for (int o = 0; o < 8; ++o) { bw1v[o] = bw1[o]; bw2v[o] = bw2[o]; }

    for (int i = blockIdx.x * 256 + t; i < n; i += gridDim.x * 256) {
        float xv = x[i];

        // ---- layer 1: h_o = silu(x)*bw1_o + cubic_{cell}(u) ----
        float s = __fmaf_rn(xv, 2.5f, 5.5f);            // (x+2.2)/0.4
        s = fminf(fmaxf(s, 0.0f), 13.999999f);
        float fc = floorf(s);
        int   c  = (int)fc;
        float u  = s - fc;
        float sx = silu_fast(xv);

        float h[8];
#pragma unroll
        for (int o = 0; o < 8; ++o) {
            float4 A = c1[c * STRIDE + o];
            float p = __fmaf_rn(__fmaf_rn(__fmaf_rn(A.w, u, A.z), u, A.y),
                                u, A.x);
            h[o] = __fmaf_rn(sx, bw1v[o], p);
        }

        // ---- layer 2: out = sum_i silu(h_i)*bw2_i + cubic_{cell_i}(u_i) ----
        float acc = 0.0f;
#pragma unroll
        for (int o = 0; o < 8; ++o) {
            float hv = h[o];
            float s2 = __fmaf_rn(hv, 2.5f, 5.5f);
            s2 = fminf(fmaxf(s2, 0.0f), 13.999999f);
            float fc2 = floorf(s2);
            int   cc  = (int)fc2;
            float uu  = s2 - fc2;
            float4 A = c2[cc * STRIDE + o];
            float p = __fmaf_rn(__fmaf_rn(__fmaf_rn(A.w, uu, A.z), uu, A.y),
                                uu, A.x);
            acc = __fmaf_rn(silu_fast(hv), bw2v[o], acc + p);
        }
        out[i] = acc;
    }
}

extern "C" void kernel_launch(void* const* d_in, const int* in_sizes, int n_in,
                              void* d_out, int out_size, void* d_ws, size_t ws_size,
                              hipStream_t stream) {
    const float* x   = (const float*)d_in[0];
    const float* bw1 = (const float*)d_in[1];
    const float* sw1 = (const float*)d_in[2];
    const float* sc1 = (const float*)d_in[3];
    const float* bw2 = (const float*)d_in[4];
    const float* sw2 = (const float*)d_in[5];
    const float* sc2 = (const float*)d_in[6];
    float* out = (float*)d_out;
    (void)d_ws; (void)ws_size;

    int n = in_sizes[0];                 // B = 524288
    int blocks = (n + 255) / 256;        // 2048 -> 8 blocks/CU

    kan2_cell<<<blocks, 256, 0, stream>>>(
        bw1, sw1, sc1, bw2, sw2, sc2, x, out, n);
}